// Round 2
// baseline (20999.323 us; speedup 1.0000x reference)
//
#include <hip/hip_runtime.h>
#include <hip/hip_bf16.h>

#define B_ 32
#define S_ 512
#define V_ 8000
#define I_ 256
#define H_ 512
#define LN_EPS 1e-5f
#define NS_ 64      // slice blocks in scan
#define SL_ 8       // H_/NS_ output rows per block

// ---------------- transpose: out[c][r] = in[r][c] (for W_in only) ----------------
__global__ void k_transpose(const float* __restrict__ in, float* __restrict__ out,
                            int R, int C) {
    __shared__ float tile[32][33];
    int c0 = blockIdx.x * 32, r0 = blockIdx.y * 32;
    int tx = threadIdx.x, ty = threadIdx.y;  // block (32,8)
#pragma unroll
    for (int i = 0; i < 32; i += 8)
        tile[ty + i][tx] = in[(size_t)(r0 + ty + i) * C + (c0 + tx)];
    __syncthreads();
#pragma unroll
    for (int i = 0; i < 32; i += 8)
        out[(size_t)(c0 + ty + i) * R + (r0 + tx)] = tile[tx][ty + i];
}

// ---------------- embed gather + input projection -> Xp_t[s][j][b] ----------------
__global__ __launch_bounds__(512) void k_embed_proj(
        const int* __restrict__ x_idx, const float* __restrict__ emb,
        const float* __restrict__ WinT, const float* __restrict__ b_in,
        float* __restrict__ Xp_t) {
    __shared__ float e[8][I_];
    __shared__ float xt[8][516];
    const int m0 = blockIdx.x * 8;           // 8 consecutive m = s*32+b, same s
    const int t = threadIdx.x;

    {   // cooperative load of 8 embedding rows
        int r = t >> 6, i4 = (t & 63) * 4;
        int m = m0 + r;
        int s = m >> 5, bb = m & 31;
        int idx = x_idx[bb * S_ + s];
        *(float4*)&e[r][i4] = *(const float4*)&emb[(size_t)idx * I_ + i4];
    }
    __syncthreads();

    const int j = t;
    float acc[8];
    const float bj = b_in[j];
#pragma unroll
    for (int r = 0; r < 8; ++r) acc[r] = bj;

    for (int i = 0; i < I_; ++i) {
        float w = WinT[(size_t)i * H_ + j];   // coalesced across threads
#pragma unroll
        for (int r = 0; r < 8; ++r) acc[r] += e[r][i] * w;
    }
    // transpose in LDS, write Xp_t[s][j][b] coalesced
#pragma unroll
    for (int r = 0; r < 8; ++r) xt[r][j] = acc[r];
    __syncthreads();
    const int s_blk = m0 >> 5, b0 = m0 & 31;
    for (int q = t; q < 1024; q += 512) {     // 1024 float4 chunks of [512 j][8 b]
        int jq = q >> 1, brel4 = (q & 1) * 4;
        float4 o;
        o.x = xt[brel4 + 0][jq];
        o.y = xt[brel4 + 1][jq];
        o.z = xt[brel4 + 2][jq];
        o.w = xt[brel4 + 3][jq];
        *(float4*)&Xp_t[((size_t)s_blk * H_ + jq) * B_ + b0 + brel4] = o;
    }
}

// ---------------- split-slice persistent scan ----------------
// 64 blocks x 256 threads. Block owns output rows j in [bid*8, bid*8+8) of both
// W_rec and W_tr (LDS-resident). Per step: GEMV-A (h_t) -> barrier -> GEMV-B (u)
// + LN partials -> barrier. LN applied during next step's staging of h into LDS.
__global__ __launch_bounds__(256) void k_scan_split(
        const float* __restrict__ Xp_t,
        const float* __restrict__ W_rec, const float* __restrict__ b_rec,
        const float* __restrict__ W_tr,  const float* __restrict__ b_tr,
        const float* __restrict__ gamma, const float* __restrict__ beta,
        float* __restrict__ u_g, float* __restrict__ ht_g,
        float2* __restrict__ partials, unsigned int* __restrict__ flags,
        float* __restrict__ hs_t) {
    __shared__ float Wr[SL_][H_];
    __shared__ float Wt[SL_][H_];
    __shared__ float hl[H_][36];      // [k][b], stride 36: float4-aligned, conflict-free reads
    __shared__ float2 red2[8][32];
    __shared__ float2 mv[32];

    const int bid = blockIdx.x;
    const int t = threadIdx.x;
    const int jrel = t >> 5, b = t & 31;
    const int j = bid * SL_ + jrel;
    const int k0own = bid * SL_;

    // preload weight slices into LDS (once)
    for (int q = t; q < SL_ * H_ / 4; q += 256) {
        int row = q >> 7, c4 = (q & 127) * 4;
        *(float4*)&Wr[row][c4] = *(const float4*)&W_rec[(size_t)(k0own + row) * H_ + c4];
        *(float4*)&Wt[row][c4] = *(const float4*)&W_tr[(size_t)(k0own + row) * H_ + c4];
    }
    const float brj = b_rec[j], btj = b_tr[j];
    const float g0 = gamma[t], g1 = gamma[t + 256];
    const float be0 = beta[t], be1 = beta[t + 256];
    __syncthreads();

    for (int s = 0; s <= S_; ++s) {
        if (s > 0) {
            // ---- LN scalars from partials (all blocks redundantly) ----
            float2 pa = {0.f, 0.f};
            for (int p = t; p < NS_ * 32; p += 256) {
                float2 v = partials[p];
                pa.x += v.x; pa.y += v.y;
            }
            red2[t >> 5][t & 31] = pa;
            __syncthreads();
            if (t < 32) {
                float s1 = 0.f, s2 = 0.f;
#pragma unroll
                for (int g = 0; g < 8; ++g) { s1 += red2[g][t].x; s2 += red2[g][t].y; }
                float m = s1 * (1.0f / H_);
                float var = s2 * (1.0f / H_) - m * m;
                mv[t] = make_float2(m, rsqrtf(var + LN_EPS));
            }
            __syncthreads();
            // ---- stage h_new = LN(u) into hl; write hs_t[s-1] for owned k ----
#pragma unroll
            for (int kk = 0; kk < 2; ++kk) {
                const int k = t + kk * 256;
                const float gk = kk ? g1 : g0, bek = kk ? be1 : be0;
                const float* up = &u_g[k * B_];
                float* hsp = &hs_t[((size_t)(s - 1) * H_ + k) * B_];
                const bool own = (k >= k0own) && (k < k0own + SL_);
#pragma unroll
                for (int c = 0; c < 32; c += 4) {
                    float4 u4 = *(const float4*)&up[c];
                    float2 mv0 = mv[c + 0], mv1 = mv[c + 1], mv2 = mv[c + 2], mv3 = mv[c + 3];
                    float4 hn;
                    hn.x = (u4.x - mv0.x) * mv0.y * gk + bek;
                    hn.y = (u4.y - mv1.x) * mv1.y * gk + bek;
                    hn.z = (u4.z - mv2.x) * mv2.y * gk + bek;
                    hn.w = (u4.w - mv3.x) * mv3.y * gk + bek;
                    if (s < S_) *(float4*)&hl[k][c] = hn;
                    if (own)    *(float4*)&hsp[c] = hn;
                }
            }
        }
        if (s == S_) break;
        __syncthreads();

        // ---- GEMV A: h_t[b][j] = tanh(Xp + b_rec + sum_k h[b][k] W_rec[j][k]) ----
        float a0 = 0.f, a1 = 0.f, a2 = 0.f, a3 = 0.f;
        if (s > 0) {
#pragma unroll 4
            for (int k = 0; k < H_; k += 4) {
                float4 w4 = *(const float4*)&Wr[jrel][k];
                a0 += hl[k + 0][b] * w4.x;
                a1 += hl[k + 1][b] * w4.y;
                a2 += hl[k + 2][b] * w4.z;
                a3 += hl[k + 3][b] * w4.w;
            }
        }
        float accA = Xp_t[((size_t)s * H_ + j) * B_ + b] + brj + ((a0 + a1) + (a2 + a3));
        float htv = tanhf(accA);
        ht_g[j * B_ + b] = htv;
        __threadfence();
        __syncthreads();
        if (t == 0)
            __hip_atomic_store(&flags[bid], (unsigned)(2 * s + 1), __ATOMIC_RELEASE, __HIP_MEMORY_SCOPE_AGENT);
        if (t < NS_) {
            while (__hip_atomic_load(&flags[t], __ATOMIC_RELAXED, __HIP_MEMORY_SCOPE_AGENT) < (unsigned)(2 * s + 1))
                __builtin_amdgcn_s_sleep(2);
        }
        __syncthreads();
        __threadfence();

        // ---- stage h_t into hl ----
#pragma unroll
        for (int kk = 0; kk < 2; ++kk) {
            const int k = t + kk * 256;
            const float* hp = &ht_g[k * B_];
#pragma unroll
            for (int c = 0; c < 32; c += 4)
                *(float4*)&hl[k][c] = *(const float4*)&hp[c];
        }
        __syncthreads();

        // ---- GEMV B: u[b][j] = tanh(b_tr + sum_k h_t[b][k] W_tr[j][k]) ----
        float c0 = 0.f, c1 = 0.f, c2 = 0.f, c3 = 0.f;
#pragma unroll 4
        for (int k = 0; k < H_; k += 4) {
            float4 w4 = *(const float4*)&Wt[jrel][k];
            c0 += hl[k + 0][b] * w4.x;
            c1 += hl[k + 1][b] * w4.y;
            c2 += hl[k + 2][b] * w4.z;
            c3 += hl[k + 3][b] * w4.w;
        }
        float uv = tanhf(btj + ((c0 + c1) + (c2 + c3)));
        u_g[j * B_ + b] = uv;
        red2[jrel][b] = make_float2(uv, uv * uv);
        __syncthreads();
        if (t < 32) {
            float s1 = 0.f, s2 = 0.f;
#pragma unroll
            for (int g = 0; g < 8; ++g) { s1 += red2[g][t].x; s2 += red2[g][t].y; }
            partials[bid * 32 + t] = make_float2(s1, s2);
        }
        __threadfence();
        __syncthreads();
        if (t == 0)
            __hip_atomic_store(&flags[bid], (unsigned)(2 * s + 2), __ATOMIC_RELEASE, __HIP_MEMORY_SCOPE_AGENT);
        if (t < NS_) {
            while (__hip_atomic_load(&flags[t], __ATOMIC_RELAXED, __HIP_MEMORY_SCOPE_AGENT) < (unsigned)(2 * s + 2))
                __builtin_amdgcn_s_sleep(2);
        }
        __syncthreads();
        __threadfence();
    }
}

// ---------------- output GEMM: y[b,s,v] = hs_t[s][:,b] . W_out[v,:] + b_out[v] ----------------
__global__ __launch_bounds__(256) void k_out_gemm(
        const float* __restrict__ hs_t, const float* __restrict__ W_out,
        const float* __restrict__ b_out, float* __restrict__ y) {
    __shared__ float Ast[16][68];   // [k][m]
    __shared__ float Bs[16][68];    // [k][v]

    const int v0 = blockIdx.x * 64;
    const int m0 = blockIdx.y * 64;
    const int t  = threadIdx.x;
    const int tx = t & 15, ty = t >> 4;

    float acc[4][4] = {};

    for (int k0 = 0; k0 < H_; k0 += 16) {
        const int kk = t & 15;
        const int mm = (t >> 4) << 2;
#pragma unroll
        for (int q = 0; q < 4; ++q) {
            int m = m0 + mm + q;
            Ast[kk][mm + q] = hs_t[((size_t)(m >> 5) * H_ + k0 + kk) * B_ + (m & 31)];
        }
#pragma unroll
        for (int q = 0; q < 4; ++q)
            Bs[kk][mm + q] = W_out[(size_t)(v0 + mm + q) * H_ + k0 + kk];
        __syncthreads();

#pragma unroll
        for (int k = 0; k < 16; ++k) {
            float4 a4 = *(const float4*)&Ast[k][ty * 4];
            float4 b4 = *(const float4*)&Bs[k][tx * 4];
            float a[4] = {a4.x, a4.y, a4.z, a4.w};
            float bb[4] = {b4.x, b4.y, b4.z, b4.w};
#pragma unroll
            for (int i = 0; i < 4; ++i)
#pragma unroll
                for (int jq = 0; jq < 4; ++jq)
                    acc[i][jq] += a[i] * bb[jq];
        }
        __syncthreads();
    }

#pragma unroll
    for (int i = 0; i < 4; ++i) {
        int m = m0 + ty * 4 + i;
        int s = m >> 5, b = m & 31;
        size_t row = ((size_t)b * S_ + s) * V_;
        int v = v0 + tx * 4;
        float4 r;
        r.x = acc[i][0] + b_out[v + 0];
        r.y = acc[i][1] + b_out[v + 1];
        r.z = acc[i][2] + b_out[v + 2];
        r.w = acc[i][3] + b_out[v + 3];
        *(float4*)&y[row + v] = r;
    }
}

extern "C" void kernel_launch(void* const* d_in, const int* in_sizes, int n_in,
                              void* d_out, int out_size, void* d_ws, size_t ws_size,
                              hipStream_t stream) {
    const int*   x_idx = (const int*)d_in[0];
    const float* emb   = (const float*)d_in[1];
    const float* W_in  = (const float*)d_in[2];
    const float* b_in  = (const float*)d_in[3];
    const float* W_rec = (const float*)d_in[4];
    const float* b_rec = (const float*)d_in[5];
    const float* W_tr  = (const float*)d_in[6];
    const float* b_tr  = (const float*)d_in[7];
    const float* gamma = (const float*)d_in[8];
    const float* beta  = (const float*)d_in[9];
    const float* W_out = (const float*)d_in[10];
    const float* b_out = (const float*)d_in[11];
    float* y  = (float*)d_out;
    float* ws = (float*)d_ws;

    // workspace layout (floats)
    float* WinT   = ws;                         // 256*512          = 131072
    float* Xp_t   = ws + 131072;                // [S][H][B]        = 8388608
    float* hs_t   = ws + 131072 + 8388608;      // [S][H][B]        = 8388608
    float* u_g    = hs_t + 8388608;             // [H][B]           = 16384
    float* ht_g   = u_g + 16384;                // [H][B]           = 16384
    float2* parti = (float2*)(ht_g + 16384);    // [64][32] float2  = 4096 floats
    unsigned int* flags = (unsigned int*)(ht_g + 16384 + 4096);  // 64 u32

    dim3 tb(32, 8);
    k_transpose<<<dim3(I_ / 32, H_ / 32), tb, 0, stream>>>(W_in, WinT, H_, I_);

    k_embed_proj<<<(B_ * S_) / 8, 512, 0, stream>>>(x_idx, emb, WinT, b_in, Xp_t);

    hipMemsetAsync(flags, 0, NS_ * sizeof(unsigned int), stream);

    k_scan_split<<<NS_, 256, 0, stream>>>(Xp_t, W_rec, b_rec, W_tr, b_tr,
                                          gamma, beta, u_g, ht_g, parti, flags, hs_t);

    k_out_gemm<<<dim3(V_ / 64, (B_ * S_) / 64), 256, 0, stream>>>(hs_t, W_out, b_out, y);
}

// Round 3
// 7775.442 us; speedup vs baseline: 2.7007x; 2.7007x over previous
//
#include <hip/hip_runtime.h>
#include <hip/hip_bf16.h>

#define B_ 32
#define S_ 512
#define V_ 8000
#define I_ 256
#define H_ 512
#define LN_EPS 1e-5f
// scan decomposition: 16 j-slices x 8 batch-quads = 128 blocks
#define NSL_ 16
#define NBP_ 8

// ---------------- transpose: out[c][r] = in[r][c], R,C multiples of 32 ----------------
__global__ void k_transpose(const float* __restrict__ in, float* __restrict__ out,
                            int R, int C) {
    __shared__ float tile[32][33];
    int c0 = blockIdx.x * 32, r0 = blockIdx.y * 32;
    int tx = threadIdx.x, ty = threadIdx.y;  // block (32,8)
#pragma unroll
    for (int i = 0; i < 32; i += 8)
        tile[ty + i][tx] = in[(size_t)(r0 + ty + i) * C + (c0 + tx)];
    __syncthreads();
#pragma unroll
    for (int i = 0; i < 32; i += 8)
        out[(size_t)(c0 + ty + i) * R + (r0 + tx)] = tile[tx][ty + i];
}

// ---------------- embed gather + input projection: Xp[m][j], m = s*B+b ----------------
__global__ __launch_bounds__(512) void k_embed_proj(
        const int* __restrict__ x_idx, const float* __restrict__ emb,
        const float* __restrict__ WinT, const float* __restrict__ b_in,
        float* __restrict__ Xp) {
    __shared__ float e[8][I_];
    const int m0 = blockIdx.x * 8;
    const int t = threadIdx.x;
    {
        int r = t >> 6, i4 = (t & 63) * 4;
        int m = m0 + r;
        int s = m >> 5, b = m & 31;           // m = s*B + b
        int idx = x_idx[b * S_ + s];
        *(float4*)&e[r][i4] = *(const float4*)&emb[(size_t)idx * I_ + i4];
    }
    __syncthreads();
    const int j = t;
    float acc[8];
    const float bj = b_in[j];
#pragma unroll
    for (int r = 0; r < 8; ++r) acc[r] = bj;
    for (int i = 0; i < I_; ++i) {
        float w = WinT[(size_t)i * H_ + j];
#pragma unroll
        for (int r = 0; r < 8; ++r) acc[r] += e[r][i] * w;
    }
#pragma unroll
    for (int r = 0; r < 8; ++r)
        Xp[(size_t)(m0 + r) * H_ + j] = acc[r];
}

// ---------------- distributed scan: 128 blocks x 512 threads ----------------
// block (g, bp): j-slice g (32 j's), batch rows [bp*4, bp*4+4).
// wave w: row r = w&3, k-half kh = w>>2. lane: jrel = l&31, ks = l>>5.
// All cross-block traffic via relaxed AGENT-scope atomics (sc0sc1, no fences).
__global__ __launch_bounds__(512) void k_scan_dist(
        const float* __restrict__ Xp,
        const float* __restrict__ WrecT, const float* __restrict__ b_rec,
        const float* __restrict__ WtrT,  const float* __restrict__ b_tr,
        const float* __restrict__ gamma, const float* __restrict__ beta,
        float* __restrict__ ht_pub, float* __restrict__ u_pub,
        float* __restrict__ p1, float* __restrict__ p2,
        unsigned int* __restrict__ flags, float* __restrict__ hs) {
    __shared__ float hbuf[4][H_];
    __shared__ float red[8][32];
    __shared__ float gl[H_], bl[H_];
    __shared__ float2 mv[4];

    const int bid = blockIdx.x;
    const int g = bid >> 3, bp = bid & 7;
    const int t = threadIdx.x;
    const int w = t >> 6, l = t & 63;
    const int r = w & 3, kh = w >> 2;
    const int jrel = l & 31, ks = l >> 5;
    const int j = g * 32 + jrel;
    const int R = bp * 4 + r;
    const int ks0 = kh * 256 + ks * 128;

    gl[t] = gamma[t]; bl[t] = beta[t];
    const float brj = b_rec[j], btj = b_tr[j];
    __syncthreads();

    for (int s = 0; s < S_; ++s) {
        // ================= phase A: h_t = tanh(Xp + h @ Wrec^T + b_rec) =========
        float xv = Xp[((size_t)s * B_ + R) * H_ + j];
        if (s > 0) {
            float acc = 0.f;
#pragma unroll 8
            for (int i = 0; i < 128; i += 4) {
                const int k = ks0 + i;
                const float* wp = &WrecT[(size_t)k * H_ + j];
                float w0 = wp[0], w1 = wp[H_], w2 = wp[2 * H_], w3 = wp[3 * H_];
                float4 h4 = *(const float4*)&hbuf[r][k];
                acc += h4.x * w0 + h4.y * w1 + h4.z * w2 + h4.w * w3;
            }
            acc += __shfl_xor(acc, 32);
            if (l < 32) red[w][jrel] = acc;
        }
        __syncthreads();
        if (w < 4 && l < 32) {
            float sum = (s > 0) ? (red[w][jrel] + red[w + 4][jrel]) : 0.f;
            float ht = tanhf(sum + xv + brj);
            __hip_atomic_store(&ht_pub[(size_t)R * H_ + j], ht,
                               __ATOMIC_RELAXED, __HIP_MEMORY_SCOPE_AGENT);
        }
        __syncthreads();   // drains all waves' stores (vmcnt before barrier)
        if (t == 0)
            __hip_atomic_store(&flags[bid * 16], 2u * s + 1,
                               __ATOMIC_RELEASE, __HIP_MEMORY_SCOPE_AGENT);
        if (t < NSL_)
            while (__hip_atomic_load(&flags[(t * NBP_ + bp) * 16],
                       __ATOMIC_RELAXED, __HIP_MEMORY_SCOPE_AGENT) < 2u * s + 1)
                __builtin_amdgcn_s_sleep(2);
        __syncthreads();
        __builtin_amdgcn_sched_barrier(0);
        // gather full h_t rows (each wave: its row, its k-half)
#pragma unroll
        for (int q = 0; q < 4; ++q) {
            int k = kh * 256 + q * 64 + l;
            hbuf[r][k] = __hip_atomic_load(&ht_pub[(size_t)R * H_ + k],
                             __ATOMIC_RELAXED, __HIP_MEMORY_SCOPE_AGENT);
        }
        __syncthreads();

        // ================= phase B: u = tanh(h_t @ Wtr^T + b_tr), LN partials ===
        {
            float acc = 0.f;
#pragma unroll 8
            for (int i = 0; i < 128; i += 4) {
                const int k = ks0 + i;
                const float* wp = &WtrT[(size_t)k * H_ + j];
                float w0 = wp[0], w1 = wp[H_], w2 = wp[2 * H_], w3 = wp[3 * H_];
                float4 h4 = *(const float4*)&hbuf[r][k];
                acc += h4.x * w0 + h4.y * w1 + h4.z * w2 + h4.w * w3;
            }
            acc += __shfl_xor(acc, 32);
            if (l < 32) red[w][jrel] = acc;
        }
        __syncthreads();
        if (w < 4) {
            float uv = 0.f;
            if (l < 32) {
                uv = tanhf(red[w][jrel] + red[w + 4][jrel] + btj);
                __hip_atomic_store(&u_pub[(size_t)R * H_ + j], uv,
                                   __ATOMIC_RELAXED, __HIP_MEMORY_SCOPE_AGENT);
            }
            float s1 = uv, s2 = uv * uv;
#pragma unroll
            for (int off = 32; off >= 1; off >>= 1) {
                s1 += __shfl_xor(s1, off);
                s2 += __shfl_xor(s2, off);
            }
            if (l == 0) {
                __hip_atomic_store(&p1[R * NSL_ + g], s1,
                                   __ATOMIC_RELAXED, __HIP_MEMORY_SCOPE_AGENT);
                __hip_atomic_store(&p2[R * NSL_ + g], s2,
                                   __ATOMIC_RELAXED, __HIP_MEMORY_SCOPE_AGENT);
            }
        }
        __syncthreads();
        if (t == 0)
            __hip_atomic_store(&flags[bid * 16], 2u * s + 2,
                               __ATOMIC_RELEASE, __HIP_MEMORY_SCOPE_AGENT);
        if (t < NSL_)
            while (__hip_atomic_load(&flags[(t * NBP_ + bp) * 16],
                       __ATOMIC_RELAXED, __HIP_MEMORY_SCOPE_AGENT) < 2u * s + 2)
                __builtin_amdgcn_s_sleep(2);
        __syncthreads();
        __builtin_amdgcn_sched_barrier(0);
        // gather u + partials, apply LN, stage h_new
        float ug0, ug1, ug2, ug3;
        {
            int kb = kh * 256 + l;
            ug0 = __hip_atomic_load(&u_pub[(size_t)R * H_ + kb],       __ATOMIC_RELAXED, __HIP_MEMORY_SCOPE_AGENT);
            ug1 = __hip_atomic_load(&u_pub[(size_t)R * H_ + kb + 64],  __ATOMIC_RELAXED, __HIP_MEMORY_SCOPE_AGENT);
            ug2 = __hip_atomic_load(&u_pub[(size_t)R * H_ + kb + 128], __ATOMIC_RELAXED, __HIP_MEMORY_SCOPE_AGENT);
            ug3 = __hip_atomic_load(&u_pub[(size_t)R * H_ + kb + 192], __ATOMIC_RELAXED, __HIP_MEMORY_SCOPE_AGENT);
        }
        if (w < 4) {
            float v1 = 0.f, v2 = 0.f;
            if (l < NSL_) {
                v1 = __hip_atomic_load(&p1[R * NSL_ + l], __ATOMIC_RELAXED, __HIP_MEMORY_SCOPE_AGENT);
                v2 = __hip_atomic_load(&p2[R * NSL_ + l], __ATOMIC_RELAXED, __HIP_MEMORY_SCOPE_AGENT);
            }
#pragma unroll
            for (int off = 8; off >= 1; off >>= 1) {
                v1 += __shfl_xor(v1, off);
                v2 += __shfl_xor(v2, off);
            }
            if (l == 0) {
                float mean = v1 * (1.0f / H_);
                float var  = v2 * (1.0f / H_) - mean * mean;
                mv[r] = make_float2(mean, rsqrtf(var + LN_EPS));
            }
        }
        __syncthreads();
        {
            const float m = mv[r].x, rs = mv[r].y;
            const int kb = kh * 256 + l;
            float hn0 = (ug0 - m) * rs * gl[kb]       + bl[kb];
            float hn1 = (ug1 - m) * rs * gl[kb + 64]  + bl[kb + 64];
            float hn2 = (ug2 - m) * rs * gl[kb + 128] + bl[kb + 128];
            float hn3 = (ug3 - m) * rs * gl[kb + 192] + bl[kb + 192];
            hbuf[r][kb] = hn0; hbuf[r][kb + 64] = hn1;
            hbuf[r][kb + 128] = hn2; hbuf[r][kb + 192] = hn3;
            if (g == 0) {
                float* hp = &hs[((size_t)s * B_ + R) * H_ + kb];
                __hip_atomic_store(&hp[0],   hn0, __ATOMIC_RELAXED, __HIP_MEMORY_SCOPE_AGENT);
                __hip_atomic_store(&hp[64],  hn1, __ATOMIC_RELAXED, __HIP_MEMORY_SCOPE_AGENT);
                __hip_atomic_store(&hp[128], hn2, __ATOMIC_RELAXED, __HIP_MEMORY_SCOPE_AGENT);
                __hip_atomic_store(&hp[192], hn3, __ATOMIC_RELAXED, __HIP_MEMORY_SCOPE_AGENT);
            }
        }
        __syncthreads();
    }
}

// ---------------- output GEMM: y[b,s,v] = hs[m,:] . W_out[v,:] + b_out[v] ----------------
__global__ __launch_bounds__(256) void k_out_gemm(
        const float* __restrict__ hs, const float* __restrict__ W_out,
        const float* __restrict__ b_out, float* __restrict__ y) {
    __shared__ float Ast[16][68];
    __shared__ float Bs[16][68];

    const int v0 = blockIdx.x * 64;
    const int m0 = blockIdx.y * 64;
    const int t  = threadIdx.x;
    const int tx = t & 15, ty = t >> 4;

    float acc[4][4] = {};

    for (int k0 = 0; k0 < H_; k0 += 16) {
        const int kk = t & 15;
        const int mm = (t >> 4) << 2;
#pragma unroll
        for (int q = 0; q < 4; ++q)
            Ast[kk][mm + q] = hs[(size_t)(m0 + mm + q) * H_ + k0 + kk];
#pragma unroll
        for (int q = 0; q < 4; ++q)
            Bs[kk][mm + q] = W_out[(size_t)(v0 + mm + q) * H_ + k0 + kk];
        __syncthreads();

#pragma unroll
        for (int k = 0; k < 16; ++k) {
            float4 a4 = *(const float4*)&Ast[k][ty * 4];
            float4 b4 = *(const float4*)&Bs[k][tx * 4];
            float a[4] = {a4.x, a4.y, a4.z, a4.w};
            float bb[4] = {b4.x, b4.y, b4.z, b4.w};
#pragma unroll
            for (int i = 0; i < 4; ++i)
#pragma unroll
                for (int jq = 0; jq < 4; ++jq)
                    acc[i][jq] += a[i] * bb[jq];
        }
        __syncthreads();
    }

#pragma unroll
    for (int i = 0; i < 4; ++i) {
        int m = m0 + ty * 4 + i;
        int s = m >> 5, b = m & 31;
        size_t row = ((size_t)b * S_ + s) * V_;
        int v = v0 + tx * 4;
        float4 rr;
        rr.x = acc[i][0] + b_out[v + 0];
        rr.y = acc[i][1] + b_out[v + 1];
        rr.z = acc[i][2] + b_out[v + 2];
        rr.w = acc[i][3] + b_out[v + 3];
        *(float4*)&y[row + v] = rr;
    }
}

extern "C" void kernel_launch(void* const* d_in, const int* in_sizes, int n_in,
                              void* d_out, int out_size, void* d_ws, size_t ws_size,
                              hipStream_t stream) {
    const int*   x_idx = (const int*)d_in[0];
    const float* emb   = (const float*)d_in[1];
    const float* W_in  = (const float*)d_in[2];
    const float* b_in  = (const float*)d_in[3];
    const float* W_rec = (const float*)d_in[4];
    const float* b_rec = (const float*)d_in[5];
    const float* W_tr  = (const float*)d_in[6];
    const float* b_tr  = (const float*)d_in[7];
    const float* gamma = (const float*)d_in[8];
    const float* beta  = (const float*)d_in[9];
    const float* W_out = (const float*)d_in[10];
    const float* b_out = (const float*)d_in[11];
    float* y  = (float*)d_out;
    float* ws = (float*)d_ws;

    // workspace layout (floats), total ~17.47M floats = 66.6 MB
    float* WinT   = ws;                          // 131072
    float* WrecT  = ws + 131072;                 // 262144
    float* WtrT   = ws + 393216;                 // 262144
    float* Xp     = ws + 655360;                 // 8388608
    float* hs     = ws + 9043968;                // 8388608
    float* ht_pub = ws + 17432576;               // 16384
    float* u_pub  = ws + 17448960;               // 16384
    float* p1     = ws + 17465344;               // 512
    float* p2     = ws + 17465856;               // 512
    unsigned int* flags = (unsigned int*)(ws + 17466368);  // 128*16 u32

    dim3 tb(32, 8);
    k_transpose<<<dim3(I_ / 32, H_ / 32), tb, 0, stream>>>(W_in,  WinT,  H_, I_);
    k_transpose<<<dim3(H_ / 32, H_ / 32), tb, 0, stream>>>(W_rec, WrecT, H_, H_);
    k_transpose<<<dim3(H_ / 32, H_ / 32), tb, 0, stream>>>(W_tr,  WtrT,  H_, H_);

    k_embed_proj<<<(B_ * S_) / 8, 512, 0, stream>>>(x_idx, emb, WinT, b_in, Xp);

    hipMemsetAsync(flags, 0, NSL_ * NBP_ * 16 * sizeof(unsigned int), stream);

    k_scan_dist<<<NSL_ * NBP_, 512, 0, stream>>>(Xp, WrecT, b_rec, WtrT, b_tr,
                                                 gamma, beta, ht_pub, u_pub,
                                                 p1, p2, flags, hs);

    k_out_gemm<<<dim3(V_ / 64, (B_ * S_) / 64), 256, 0, stream>>>(hs, W_out, b_out, y);
}